// Round 1
// baseline (576.802 us; speedup 1.0000x reference)
//
#include <hip/hip_runtime.h>

#define NN 50000
#define NE 800000
#define DD 128
#define LN_EPS 1e-5f

// ---------------- CSR build ----------------

__global__ void zero_counts(int* __restrict__ counts) {
    int i = blockIdx.x * 256 + threadIdx.x;
    if (i < NN) counts[i] = 0;
}

__global__ void hist_kernel(const int* __restrict__ dst, int* __restrict__ counts) {
    int e = blockIdx.x * 256 + threadIdx.x;
    if (e < NE) atomicAdd(&counts[dst[e]], 1);
}

// per-256-block exclusive scan; emits block sums
__global__ void scan_blocks(const int* __restrict__ counts, int* __restrict__ excl,
                            int* __restrict__ block_sums) {
    __shared__ int ws[5];
    int gid = blockIdx.x * 256 + threadIdx.x;
    int lane = threadIdx.x & 63, wid = threadIdx.x >> 6;
    int v = (gid < NN) ? counts[gid] : 0;
    int x = v;
#pragma unroll
    for (int off = 1; off < 64; off <<= 1) {
        int t = __shfl_up(x, off, 64);
        if (lane >= off) x += t;
    }
    if (lane == 63) ws[wid] = x;
    __syncthreads();
    if (threadIdx.x == 0) {
        int run = 0;
        for (int i = 0; i < 4; ++i) { int t = ws[i]; ws[i] = run; run += t; }
        ws[4] = run;
    }
    __syncthreads();
    if (gid < NN) excl[gid] = x - v + ws[wid];
    if (threadIdx.x == 0) block_sums[blockIdx.x] = ws[4];
}

// single-block exclusive scan of the block sums (nb <= 256)
__global__ void scan_sums_kernel(int* __restrict__ bsums, int nb) {
    __shared__ int ws[5];
    int lane = threadIdx.x & 63, wid = threadIdx.x >> 6;
    int v = (threadIdx.x < nb) ? bsums[threadIdx.x] : 0;
    int x = v;
#pragma unroll
    for (int off = 1; off < 64; off <<= 1) {
        int t = __shfl_up(x, off, 64);
        if (lane >= off) x += t;
    }
    if (lane == 63) ws[wid] = x;
    __syncthreads();
    if (threadIdx.x == 0) {
        int run = 0;
        for (int i = 0; i < 4; ++i) { int t = ws[i]; ws[i] = run; run += t; }
    }
    __syncthreads();
    if (threadIdx.x < nb) bsums[threadIdx.x] = x - v + ws[wid];
}

__global__ void finalize_kernel(const int* __restrict__ excl, const int* __restrict__ bsums,
                                const int* __restrict__ counts, int* __restrict__ row_ptr,
                                int* __restrict__ next_pos, float* __restrict__ dinv) {
    int gid = blockIdx.x * 256 + threadIdx.x;
    if (gid < NN) {
        int rp = excl[gid] + bsums[blockIdx.x];
        row_ptr[gid] = rp;
        next_pos[gid] = rp;
        dinv[gid] = rsqrtf((float)counts[gid] + 1.0f);  // deg = in-degree + 1 (self loop)
    }
    if (blockIdx.x == 0 && threadIdx.x == 0) row_ptr[NN] = NE;
}

__global__ void fill_kernel(const int* __restrict__ src, const int* __restrict__ dst,
                            int* __restrict__ next_pos, const float* __restrict__ dinv,
                            int* __restrict__ src_sorted, float* __restrict__ nrm_sorted) {
    int e = blockIdx.x * 256 + threadIdx.x;
    if (e < NE) {
        int s = src[e], d = dst[e];
        int pos = atomicAdd(&next_pos[d], 1);
        src_sorted[pos] = s;
        nrm_sorted[pos] = dinv[s] * dinv[d];
    }
}

// ---------------- per-layer: aggregate (pre-GEMM, linearity) ----------------
// agg[i,:] = sum_{(s->i)} dinv[s]*dinv[i] * cur[s,:] + dinv[i]^2 * cur[i,:]
// one wave (64 lanes) per node; float2 per lane covers D=128.
__global__ void agg_kernel(const float* __restrict__ cur, const int* __restrict__ row_ptr,
                           const int* __restrict__ src_sorted, const float* __restrict__ nrm,
                           const float* __restrict__ dinv, float* __restrict__ aggbuf) {
    int node = blockIdx.x * 4 + (threadIdx.x >> 6);  // grid 12500 * 4 waves = 50000 exact
    int lane = threadIdx.x & 63;
    int beg = row_ptr[node], end = row_ptr[node + 1];
    const float2* cur2 = (const float2*)cur;
    float ax = 0.f, ay = 0.f;
    for (int e = beg; e < end; ++e) {
        int s = src_sorted[e];
        float w = nrm[e];
        float2 v = cur2[s * 64 + lane];
        ax = fmaf(w, v.x, ax);
        ay = fmaf(w, v.y, ay);
    }
    float di = dinv[node];
    float w2 = di * di;
    float2 sv = cur2[node * 64 + lane];
    ax = fmaf(w2, sv.x, ax);
    ay = fmaf(w2, sv.y, ay);
    float2 o; o.x = ax; o.y = ay;
    ((float2*)aggbuf)[node * 64 + lane] = o;
}

// ---------------- per-layer: fused GEMM + bias + LayerNorm + ReLU + residual ----------------
// out[i,:] = (l>0 ? out[i,:] : 0) + relu(LN(agg[i,:] @ W + b))
// Block: 256 threads = 32 col-groups (4 cols) x 8 row-slots (4 rows) -> 32 rows/block.
// LDS: W 64KB + 32 agg rows 16KB = 80KB exactly -> 2 blocks/CU.
template <bool RES>
__global__ __launch_bounds__(256) void gemm_ln_kernel(
    const float* __restrict__ agg, const float* __restrict__ W, const float* __restrict__ bias,
    const float* __restrict__ gamma, const float* __restrict__ beta, float* __restrict__ out) {
    __shared__ float4 sW4[DD * DD / 4];  // W[k][c] at sW4[k*32 + c/4]
    __shared__ float4 sA4[32 * DD / 4];  // row r at sA4[r*32 + k/4]

    const float4* Wg = (const float4*)W;
    for (int i = threadIdx.x; i < DD * DD / 4; i += 256) sW4[i] = Wg[i];

    int row0 = blockIdx.x * 32;
    int nrows = min(32, NN - row0);
    const float4* Ag = (const float4*)(agg + (long)row0 * DD);
    for (int i = threadIdx.x; i < nrows * (DD / 4); i += 256) sA4[i] = Ag[i];
    for (int i = nrows * (DD / 4) + threadIdx.x; i < 32 * (DD / 4); i += 256)
        sA4[i] = make_float4(0.f, 0.f, 0.f, 0.f);
    __syncthreads();

    int cg = threadIdx.x & 31;   // cols 4*cg .. 4*cg+3
    int rs = threadIdx.x >> 5;   // rows rs*4 .. rs*4+3 (local)
    float acc[4][4] = {};

#pragma unroll 2
    for (int k = 0; k < DD; k += 4) {
        float4 w0 = sW4[(k + 0) * 32 + cg];
        float4 w1 = sW4[(k + 1) * 32 + cg];
        float4 w2 = sW4[(k + 2) * 32 + cg];
        float4 w3 = sW4[(k + 3) * 32 + cg];
#pragma unroll
        for (int r = 0; r < 4; ++r) {
            float4 a = sA4[(rs * 4 + r) * 32 + (k >> 2)];
            acc[r][0] += a.x * w0.x + a.y * w1.x + a.z * w2.x + a.w * w3.x;
            acc[r][1] += a.x * w0.y + a.y * w1.y + a.z * w2.y + a.w * w3.y;
            acc[r][2] += a.x * w0.z + a.y * w1.z + a.z * w2.z + a.w * w3.z;
            acc[r][3] += a.x * w0.w + a.y * w1.w + a.z * w2.w + a.w * w3.w;
        }
    }

    float4 b4 = ((const float4*)bias)[cg];
    float4 g4 = ((const float4*)gamma)[cg];
    float4 be4 = ((const float4*)beta)[cg];

#pragma unroll
    for (int r = 0; r < 4; ++r) {
        int row = row0 + rs * 4 + r;
        float yx = acc[r][0] + b4.x;
        float yy = acc[r][1] + b4.y;
        float yz = acc[r][2] + b4.z;
        float yw = acc[r][3] + b4.w;
        // LN over the 32 lanes of this row-slot (half-wave: rs pairs share a wave,
        // xor offsets <32 never cross the 32-lane halves)
        float s1 = yx + yy + yz + yw;
        float s2 = yx * yx + yy * yy + yz * yz + yw * yw;
#pragma unroll
        for (int off = 16; off >= 1; off >>= 1) {
            s1 += __shfl_xor(s1, off, 64);
            s2 += __shfl_xor(s2, off, 64);
        }
        float mu = s1 * (1.f / 128.f);
        float var = s2 * (1.f / 128.f) - mu * mu;
        float rstd = rsqrtf(var + LN_EPS);
        float ox = fmaxf((yx - mu) * rstd * g4.x + be4.x, 0.f);
        float oy = fmaxf((yy - mu) * rstd * g4.y + be4.y, 0.f);
        float oz = fmaxf((yz - mu) * rstd * g4.z + be4.z, 0.f);
        float ow = fmaxf((yw - mu) * rstd * g4.w + be4.w, 0.f);
        if (row < NN) {
            float4* op = (float4*)out + (long)row * 32 + cg;
            float4 o = make_float4(ox, oy, oz, ow);
            if (RES) {
                float4 pv = *op;
                o.x += pv.x; o.y += pv.y; o.z += pv.z; o.w += pv.w;
            }
            *op = o;
        }
    }
}

// ---------------- launch ----------------

extern "C" void kernel_launch(void* const* d_in, const int* in_sizes, int n_in,
                              void* d_out, int out_size, void* d_ws, size_t ws_size,
                              hipStream_t stream) {
    const float* x = (const float*)d_in[0];
    const int* edge = (const int*)d_in[1];
    const float* Ws = (const float*)d_in[2];
    const float* bs = (const float*)d_in[3];
    const float* gs = (const float*)d_in[4];
    const float* bes = (const float*)d_in[5];
    float* out = (float*)d_out;
    const int* src = edge;       // edge_index[0]
    const int* dst = edge + NE;  // edge_index[1]

    char* p = (char*)d_ws;
    int* counts = (int*)p;      p += (size_t)NN * 4;
    int* excl = (int*)p;        p += (size_t)NN * 4;
    int* bsums = (int*)p;       p += 256 * 4;
    int* row_ptr = (int*)p;     p += (size_t)(NN + 4) * 4;  // +4 keeps 16B alignment downstream
    int* next_pos = (int*)p;    p += (size_t)NN * 4;
    float* dinv = (float*)p;    p += (size_t)NN * 4;
    int* src_sorted = (int*)p;  p += (size_t)NE * 4;
    float* nrm_sorted = (float*)p; p += (size_t)NE * 4;
    float* aggbuf = (float*)p;  p += (size_t)NN * DD * 4;

    zero_counts<<<196, 256, 0, stream>>>(counts);
    hist_kernel<<<NE / 256, 256, 0, stream>>>(dst, counts);
    scan_blocks<<<196, 256, 0, stream>>>(counts, excl, bsums);
    scan_sums_kernel<<<1, 256, 0, stream>>>(bsums, 196);
    finalize_kernel<<<196, 256, 0, stream>>>(excl, bsums, counts, row_ptr, next_pos, dinv);
    fill_kernel<<<NE / 256, 256, 0, stream>>>(src, dst, next_pos, dinv, src_sorted, nrm_sorted);

    for (int l = 0; l < 3; ++l) {
        const float* cur = (l == 0) ? x : out;
        agg_kernel<<<NN / 4, 256, 0, stream>>>(cur, row_ptr, src_sorted, nrm_sorted, dinv, aggbuf);
        if (l == 0)
            gemm_ln_kernel<false><<<(NN + 31) / 32, 256, 0, stream>>>(
                aggbuf, Ws + (size_t)l * DD * DD, bs + l * DD, gs + l * DD, bes + l * DD, out);
        else
            gemm_ln_kernel<true><<<(NN + 31) / 32, 256, 0, stream>>>(
                aggbuf, Ws + (size_t)l * DD * DD, bs + l * DD, gs + l * DD, bes + l * DD, out);
    }
}

// Round 2
// 450.335 us; speedup vs baseline: 1.2808x; 1.2808x over previous
//
#include <hip/hip_runtime.h>
#include <hip/hip_bf16.h>

#define NN 50000
#define NE 800000
#define DD 128
#define LN_EPS 1e-5f

// ---------------- CSR build ----------------

__global__ void zero_counts(int* __restrict__ counts) {
    int i = blockIdx.x * 256 + threadIdx.x;
    if (i < NN) counts[i] = 0;
}

__global__ void hist_kernel(const int* __restrict__ dst, int* __restrict__ counts) {
    int e = blockIdx.x * 256 + threadIdx.x;
    if (e < NE) atomicAdd(&counts[dst[e]], 1);
}

// per-256-block exclusive scan; emits block sums
__global__ void scan_blocks(const int* __restrict__ counts, int* __restrict__ excl,
                            int* __restrict__ block_sums) {
    __shared__ int ws[5];
    int gid = blockIdx.x * 256 + threadIdx.x;
    int lane = threadIdx.x & 63, wid = threadIdx.x >> 6;
    int v = (gid < NN) ? counts[gid] : 0;
    int x = v;
#pragma unroll
    for (int off = 1; off < 64; off <<= 1) {
        int t = __shfl_up(x, off, 64);
        if (lane >= off) x += t;
    }
    if (lane == 63) ws[wid] = x;
    __syncthreads();
    if (threadIdx.x == 0) {
        int run = 0;
        for (int i = 0; i < 4; ++i) { int t = ws[i]; ws[i] = run; run += t; }
        ws[4] = run;
    }
    __syncthreads();
    if (gid < NN) excl[gid] = x - v + ws[wid];
    if (threadIdx.x == 0) block_sums[blockIdx.x] = ws[4];
}

// single-block exclusive scan of the block sums (nb <= 256)
__global__ void scan_sums_kernel(int* __restrict__ bsums, int nb) {
    __shared__ int ws[5];
    int lane = threadIdx.x & 63, wid = threadIdx.x >> 6;
    int v = (threadIdx.x < nb) ? bsums[threadIdx.x] : 0;
    int x = v;
#pragma unroll
    for (int off = 1; off < 64; off <<= 1) {
        int t = __shfl_up(x, off, 64);
        if (lane >= off) x += t;
    }
    if (lane == 63) ws[wid] = x;
    __syncthreads();
    if (threadIdx.x == 0) {
        int run = 0;
        for (int i = 0; i < 4; ++i) { int t = ws[i]; ws[i] = run; run += t; }
    }
    __syncthreads();
    if (threadIdx.x < nb) bsums[threadIdx.x] = x - v + ws[wid];
}

__global__ void finalize_kernel(const int* __restrict__ excl, const int* __restrict__ bsums,
                                const int* __restrict__ counts, int* __restrict__ row_ptr,
                                int* __restrict__ next_pos, float* __restrict__ dinv) {
    int gid = blockIdx.x * 256 + threadIdx.x;
    if (gid < NN) {
        int rp = excl[gid] + bsums[blockIdx.x];
        row_ptr[gid] = rp;
        next_pos[gid] = rp;
        dinv[gid] = rsqrtf((float)counts[gid] + 1.0f);  // deg = in-degree + 1 (self loop)
    }
    if (blockIdx.x == 0 && threadIdx.x == 0) row_ptr[NN] = NE;
}

__global__ void fill_kernel(const int* __restrict__ src, const int* __restrict__ dst,
                            int* __restrict__ next_pos, const float* __restrict__ dinv,
                            int* __restrict__ src_sorted, float* __restrict__ nrm_sorted) {
    int e = blockIdx.x * 256 + threadIdx.x;
    if (e < NE) {
        int s = src[e], d = dst[e];
        int pos = atomicAdd(&next_pos[d], 1);
        src_sorted[pos] = s;
        nrm_sorted[pos] = dinv[s] * dinv[d];
    }
}

// ---------------- fp32 -> bf16 feature cast (layer 0 input only) ----------------
__global__ void cast_kernel(const float* __restrict__ in, __hip_bfloat162* __restrict__ outb) {
    int i = blockIdx.x * 256 + threadIdx.x;  // over NN*64 float2 groups
    float2 v = ((const float2*)in)[i];
    __hip_bfloat162 o;
    o.x = __float2bfloat16(v.x);
    o.y = __float2bfloat16(v.y);
    outb[i] = o;
}

// ---------------- per-layer: aggregate (pre-GEMM, linearity), bf16 gather ----------------
// agg[i,:] = sum_{(s->i)} dinv[s]*dinv[i] * cur[s,:] + dinv[i]^2 * cur[i,:]
// one wave per node; bfloat162 per lane covers D=128 (256 B/row = 2 cache lines).
// Edge loop unrolled x4: 4 independent gathers in flight per wave.
__global__ void agg_kernel(const __hip_bfloat162* __restrict__ curb,
                           const int* __restrict__ row_ptr,
                           const int* __restrict__ src_sorted, const float* __restrict__ nrm,
                           const float* __restrict__ dinv, float* __restrict__ aggbuf) {
    int node = blockIdx.x * 4 + (threadIdx.x >> 6);  // grid 12500 * 4 waves = 50000 exact
    int lane = threadIdx.x & 63;
    int beg = row_ptr[node], end = row_ptr[node + 1];
    float ax = 0.f, ay = 0.f;
    int e = beg;
    for (; e + 4 <= end; e += 4) {
        int s0 = src_sorted[e + 0];
        int s1 = src_sorted[e + 1];
        int s2 = src_sorted[e + 2];
        int s3 = src_sorted[e + 3];
        float w0 = nrm[e + 0];
        float w1 = nrm[e + 1];
        float w2 = nrm[e + 2];
        float w3 = nrm[e + 3];
        __hip_bfloat162 v0 = curb[s0 * 64 + lane];
        __hip_bfloat162 v1 = curb[s1 * 64 + lane];
        __hip_bfloat162 v2 = curb[s2 * 64 + lane];
        __hip_bfloat162 v3 = curb[s3 * 64 + lane];
        float2 f0 = __bfloat1622float2(v0);
        float2 f1 = __bfloat1622float2(v1);
        float2 f2 = __bfloat1622float2(v2);
        float2 f3 = __bfloat1622float2(v3);
        ax = fmaf(w0, f0.x, ax); ay = fmaf(w0, f0.y, ay);
        ax = fmaf(w1, f1.x, ax); ay = fmaf(w1, f1.y, ay);
        ax = fmaf(w2, f2.x, ax); ay = fmaf(w2, f2.y, ay);
        ax = fmaf(w3, f3.x, ax); ay = fmaf(w3, f3.y, ay);
    }
    for (; e < end; ++e) {
        int s = src_sorted[e];
        float w = nrm[e];
        float2 f = __bfloat1622float2(curb[s * 64 + lane]);
        ax = fmaf(w, f.x, ax);
        ay = fmaf(w, f.y, ay);
    }
    float di = dinv[node];
    float w2s = di * di;
    float2 sv = __bfloat1622float2(curb[node * 64 + lane]);
    ax = fmaf(w2s, sv.x, ax);
    ay = fmaf(w2s, sv.y, ay);
    float2 o; o.x = ax; o.y = ay;
    ((float2*)aggbuf)[node * 64 + lane] = o;
}

// ---------------- per-layer: fused GEMM + bias + LayerNorm + ReLU + residual ----------------
// out[i,:] = (RES ? out[i,:] : 0) + relu(LN(agg[i,:] @ W + b)); optional bf16 copy for next agg.
// Block: 256 threads = 32 col-groups (4 cols) x 8 row-slots (4 rows) -> 32 rows/block.
// LDS: W 64KB + 32 agg rows 16KB = 80KB exactly -> 2 blocks/CU.
template <bool RES, bool WRITEBF>
__global__ __launch_bounds__(256) void gemm_ln_kernel(
    const float* __restrict__ agg, const float* __restrict__ W, const float* __restrict__ bias,
    const float* __restrict__ gamma, const float* __restrict__ beta, float* __restrict__ out,
    uint2* __restrict__ outbf) {
    __shared__ float4 sW4[DD * DD / 4];  // W[k][c] at sW4[k*32 + c/4]
    __shared__ float4 sA4[32 * DD / 4];  // row r at sA4[r*32 + k/4]

    const float4* Wg = (const float4*)W;
    for (int i = threadIdx.x; i < DD * DD / 4; i += 256) sW4[i] = Wg[i];

    int row0 = blockIdx.x * 32;
    int nrows = min(32, NN - row0);
    const float4* Ag = (const float4*)(agg + (long)row0 * DD);
    for (int i = threadIdx.x; i < nrows * (DD / 4); i += 256) sA4[i] = Ag[i];
    for (int i = nrows * (DD / 4) + threadIdx.x; i < 32 * (DD / 4); i += 256)
        sA4[i] = make_float4(0.f, 0.f, 0.f, 0.f);
    __syncthreads();

    int cg = threadIdx.x & 31;   // cols 4*cg .. 4*cg+3
    int rs = threadIdx.x >> 5;   // rows rs*4 .. rs*4+3 (local)
    float acc[4][4] = {};

#pragma unroll 2
    for (int k = 0; k < DD; k += 4) {
        float4 w0 = sW4[(k + 0) * 32 + cg];
        float4 w1 = sW4[(k + 1) * 32 + cg];
        float4 w2 = sW4[(k + 2) * 32 + cg];
        float4 w3 = sW4[(k + 3) * 32 + cg];
#pragma unroll
        for (int r = 0; r < 4; ++r) {
            float4 a = sA4[(rs * 4 + r) * 32 + (k >> 2)];
            acc[r][0] += a.x * w0.x + a.y * w1.x + a.z * w2.x + a.w * w3.x;
            acc[r][1] += a.x * w0.y + a.y * w1.y + a.z * w2.y + a.w * w3.y;
            acc[r][2] += a.x * w0.z + a.y * w1.z + a.z * w2.z + a.w * w3.z;
            acc[r][3] += a.x * w0.w + a.y * w1.w + a.z * w2.w + a.w * w3.w;
        }
    }

    float4 b4 = ((const float4*)bias)[cg];
    float4 g4 = ((const float4*)gamma)[cg];
    float4 be4 = ((const float4*)beta)[cg];

#pragma unroll
    for (int r = 0; r < 4; ++r) {
        int row = row0 + rs * 4 + r;
        float yx = acc[r][0] + b4.x;
        float yy = acc[r][1] + b4.y;
        float yz = acc[r][2] + b4.z;
        float yw = acc[r][3] + b4.w;
        // LN over the 32 lanes of this row-slot (xor offsets <32 stay in the half-wave)
        float s1 = yx + yy + yz + yw;
        float s2 = yx * yx + yy * yy + yz * yz + yw * yw;
#pragma unroll
        for (int off = 16; off >= 1; off >>= 1) {
            s1 += __shfl_xor(s1, off, 64);
            s2 += __shfl_xor(s2, off, 64);
        }
        float mu = s1 * (1.f / 128.f);
        float var = s2 * (1.f / 128.f) - mu * mu;
        float rstd = rsqrtf(var + LN_EPS);
        float ox = fmaxf((yx - mu) * rstd * g4.x + be4.x, 0.f);
        float oy = fmaxf((yy - mu) * rstd * g4.y + be4.y, 0.f);
        float oz = fmaxf((yz - mu) * rstd * g4.z + be4.z, 0.f);
        float ow = fmaxf((yw - mu) * rstd * g4.w + be4.w, 0.f);
        if (row < NN) {
            float4* op = (float4*)out + (long)row * 32 + cg;
            float4 o = make_float4(ox, oy, oz, ow);
            if (RES) {
                float4 pv = *op;
                o.x += pv.x; o.y += pv.y; o.z += pv.z; o.w += pv.w;
            }
            *op = o;
            if (WRITEBF) {
                union { __hip_bfloat162 h2[2]; uint2 u; } pk;
                __hip_bfloat162 p0, p1;
                p0.x = __float2bfloat16(o.x); p0.y = __float2bfloat16(o.y);
                p1.x = __float2bfloat16(o.z); p1.y = __float2bfloat16(o.w);
                pk.h2[0] = p0; pk.h2[1] = p1;
                outbf[(long)row * 32 + cg] = pk.u;
            }
        }
    }
}

// ---------------- launch ----------------

extern "C" void kernel_launch(void* const* d_in, const int* in_sizes, int n_in,
                              void* d_out, int out_size, void* d_ws, size_t ws_size,
                              hipStream_t stream) {
    const float* x = (const float*)d_in[0];
    const int* edge = (const int*)d_in[1];
    const float* Ws = (const float*)d_in[2];
    const float* bs = (const float*)d_in[3];
    const float* gs = (const float*)d_in[4];
    const float* bes = (const float*)d_in[5];
    float* out = (float*)d_out;
    const int* src = edge;       // edge_index[0]
    const int* dst = edge + NE;  // edge_index[1]

    char* p = (char*)d_ws;
    int* counts = (int*)p;      p += (size_t)NN * 4;
    int* excl = (int*)p;        p += (size_t)NN * 4;
    int* bsums = (int*)p;       p += 256 * 4;
    int* row_ptr = (int*)p;     p += (size_t)(NN + 4) * 4;  // +4 keeps 16B alignment downstream
    int* next_pos = (int*)p;    p += (size_t)NN * 4;
    float* dinv = (float*)p;    p += (size_t)NN * 4;
    int* src_sorted = (int*)p;  p += (size_t)NE * 4;
    float* nrm_sorted = (float*)p; p += (size_t)NE * 4;
    float* aggbuf = (float*)p;  p += (size_t)NN * DD * 4;
    __hip_bfloat162* featb = (__hip_bfloat162*)p; p += (size_t)NN * DD * 2;  // bf16 gather table

    zero_counts<<<196, 256, 0, stream>>>(counts);
    hist_kernel<<<NE / 256, 256, 0, stream>>>(dst, counts);
    scan_blocks<<<196, 256, 0, stream>>>(counts, excl, bsums);
    scan_sums_kernel<<<1, 256, 0, stream>>>(bsums, 196);
    finalize_kernel<<<196, 256, 0, stream>>>(excl, bsums, counts, row_ptr, next_pos, dinv);
    fill_kernel<<<NE / 256, 256, 0, stream>>>(src, dst, next_pos, dinv, src_sorted, nrm_sorted);

    cast_kernel<<<NN * 64 / 256, 256, 0, stream>>>(x, featb);

    for (int l = 0; l < 3; ++l) {
        agg_kernel<<<NN / 4, 256, 0, stream>>>(featb, row_ptr, src_sorted, nrm_sorted, dinv,
                                               aggbuf);
        const float* Wl = Ws + (size_t)l * DD * DD;
        const float* bl = bs + l * DD;
        const float* gl = gs + l * DD;
        const float* bel = bes + l * DD;
        if (l == 0)
            gemm_ln_kernel<false, true><<<(NN + 31) / 32, 256, 0, stream>>>(
                aggbuf, Wl, bl, gl, bel, out, (uint2*)featb);
        else if (l == 1)
            gemm_ln_kernel<true, true><<<(NN + 31) / 32, 256, 0, stream>>>(
                aggbuf, Wl, bl, gl, bel, out, (uint2*)featb);
        else
            gemm_ln_kernel<true, false><<<(NN + 31) / 32, 256, 0, stream>>>(
                aggbuf, Wl, bl, gl, bel, out, (uint2*)featb);
    }
}

// Round 3
// 368.078 us; speedup vs baseline: 1.5671x; 1.2235x over previous
//
#include <hip/hip_runtime.h>
#include <hip/hip_bf16.h>

#define NN 50000
#define NE 800000
#define DD 128
#define LN_EPS 1e-5f

typedef __bf16 bf16x8 __attribute__((ext_vector_type(8)));
typedef float f32x4 __attribute__((ext_vector_type(4)));

__device__ inline ushort f2bf_bits(float f) {
    union { __hip_bfloat16 h; ushort u; } c;
    c.h = __float2bfloat16(f);
    return c.u;
}

// ---------------- CSR build ----------------

__global__ void zero_counts(int* __restrict__ counts) {
    int i = blockIdx.x * 256 + threadIdx.x;
    if (i < NN) counts[i] = 0;
}

__global__ void hist_kernel(const int* __restrict__ dst, int* __restrict__ counts) {
    int e = blockIdx.x * 256 + threadIdx.x;
    if (e < NE) atomicAdd(&counts[dst[e]], 1);
}

__global__ void scan_blocks(const int* __restrict__ counts, int* __restrict__ excl,
                            int* __restrict__ block_sums) {
    __shared__ int ws[5];
    int gid = blockIdx.x * 256 + threadIdx.x;
    int lane = threadIdx.x & 63, wid = threadIdx.x >> 6;
    int v = (gid < NN) ? counts[gid] : 0;
    int x = v;
#pragma unroll
    for (int off = 1; off < 64; off <<= 1) {
        int t = __shfl_up(x, off, 64);
        if (lane >= off) x += t;
    }
    if (lane == 63) ws[wid] = x;
    __syncthreads();
    if (threadIdx.x == 0) {
        int run = 0;
        for (int i = 0; i < 4; ++i) { int t = ws[i]; ws[i] = run; run += t; }
        ws[4] = run;
    }
    __syncthreads();
    if (gid < NN) excl[gid] = x - v + ws[wid];
    if (threadIdx.x == 0) block_sums[blockIdx.x] = ws[4];
}

__global__ void scan_sums_kernel(int* __restrict__ bsums, int nb) {
    __shared__ int ws[5];
    int lane = threadIdx.x & 63, wid = threadIdx.x >> 6;
    int v = (threadIdx.x < nb) ? bsums[threadIdx.x] : 0;
    int x = v;
#pragma unroll
    for (int off = 1; off < 64; off <<= 1) {
        int t = __shfl_up(x, off, 64);
        if (lane >= off) x += t;
    }
    if (lane == 63) ws[wid] = x;
    __syncthreads();
    if (threadIdx.x == 0) {
        int run = 0;
        for (int i = 0; i < 4; ++i) { int t = ws[i]; ws[i] = run; run += t; }
    }
    __syncthreads();
    if (threadIdx.x < nb) bsums[threadIdx.x] = x - v + ws[wid];
}

__global__ void finalize_kernel(const int* __restrict__ excl, const int* __restrict__ bsums,
                                const int* __restrict__ counts, int* __restrict__ row_ptr,
                                int* __restrict__ next_pos, float* __restrict__ dinv) {
    int gid = blockIdx.x * 256 + threadIdx.x;
    if (gid < NN) {
        int rp = excl[gid] + bsums[blockIdx.x];
        row_ptr[gid] = rp;
        next_pos[gid] = rp;
        dinv[gid] = rsqrtf((float)counts[gid] + 1.0f);
    }
    if (blockIdx.x == 0 && threadIdx.x == 0) row_ptr[NN] = NE;
}

__global__ void fill_kernel(const int* __restrict__ src, const int* __restrict__ dst,
                            int* __restrict__ next_pos, const float* __restrict__ dinv,
                            int* __restrict__ src_sorted, float* __restrict__ nrm_sorted) {
    int e = blockIdx.x * 256 + threadIdx.x;
    if (e < NE) {
        int s = src[e], d = dst[e];
        int pos = atomicAdd(&next_pos[d], 1);
        src_sorted[pos] = s;
        nrm_sorted[pos] = dinv[s] * dinv[d];
    }
}

// ---------------- casts ----------------

// x fp32 -> featb bf16
__global__ void cast_kernel(const float* __restrict__ in, ushort* __restrict__ outb) {
    int i = blockIdx.x * 256 + threadIdx.x;  // over NN*64 float2 groups
    float2 v = ((const float2*)in)[i];
    ushort2 o;
    o.x = f2bf_bits(v.x);
    o.y = f2bf_bits(v.y);
    ((ushort2*)outb)[i] = o;
}

// Ws fp32 [l][k][n] -> Wt bf16 [l][n][k] (transposed for MFMA B-fragment b128 reads)
__global__ void wtcast_kernel(const float* __restrict__ W, ushort* __restrict__ Wt) {
    int i = blockIdx.x * 256 + threadIdx.x;  // 3*128*128 = 49152
    int l = i >> 14, k = (i >> 7) & 127, n = i & 127;
    Wt[l * 16384 + n * 128 + k] = f2bf_bits(W[i]);
}

// ---------------- per-layer: aggregate (pre-GEMM, linearity), bf16 gather ----------------
// agg[i,:] = sum_{(s->i)} dinv[s]*dinv[i]*cur[s,:] + dinv[i]^2*cur[i,:]
// 4 nodes per wave (16 lanes x 16B chunk each), edge loop unrolled x4
// -> 16 outstanding gathers per wave (MLP was the round-2 limiter).
__device__ inline void accum8(float* acc, uint4 v, float w) {
    uint vv[4] = {v.x, v.y, v.z, v.w};
#pragma unroll
    for (int i = 0; i < 4; ++i) {
        float lo = __uint_as_float(vv[i] << 16);
        float hi = __uint_as_float(vv[i] & 0xffff0000u);
        acc[2 * i] = fmaf(w, lo, acc[2 * i]);
        acc[2 * i + 1] = fmaf(w, hi, acc[2 * i + 1]);
    }
}

__global__ __launch_bounds__(256) void agg_kernel(
    const ushort* __restrict__ curb, const int* __restrict__ row_ptr,
    const int* __restrict__ src_sorted, const float* __restrict__ nrm,
    const float* __restrict__ dinv, ushort* __restrict__ aggb) {
    int wavei = threadIdx.x >> 6;
    int lane = threadIdx.x & 63;
    int g = lane >> 4, t = lane & 15;
    int node = blockIdx.x * 16 + wavei * 4 + g;  // grid 3125*16 = 50000 exact
    int beg = row_ptr[node], end = row_ptr[node + 1];
    const uint4* cu4 = (const uint4*)curb;  // row = 16 x 16B chunks
    float acc[8] = {};
    int e = beg;
    for (; e + 4 <= end; e += 4) {
        int s0 = src_sorted[e + 0];
        int s1 = src_sorted[e + 1];
        int s2 = src_sorted[e + 2];
        int s3 = src_sorted[e + 3];
        float w0 = nrm[e + 0], w1 = nrm[e + 1], w2 = nrm[e + 2], w3 = nrm[e + 3];
        uint4 v0 = cu4[s0 * 16 + t];
        uint4 v1 = cu4[s1 * 16 + t];
        uint4 v2 = cu4[s2 * 16 + t];
        uint4 v3 = cu4[s3 * 16 + t];
        accum8(acc, v0, w0);
        accum8(acc, v1, w1);
        accum8(acc, v2, w2);
        accum8(acc, v3, w3);
    }
    for (; e < end; ++e) {
        int s = src_sorted[e];
        float w = nrm[e];
        accum8(acc, cu4[s * 16 + t], w);
    }
    float di = dinv[node];
    accum8(acc, cu4[node * 16 + t], di * di);
    union { ushort us[8]; uint4 u; } pk;
#pragma unroll
    for (int i = 0; i < 8; ++i) pk.us[i] = f2bf_bits(acc[i]);
    ((uint4*)aggb)[node * 16 + t] = pk.u;
}

// ---------------- per-layer: MFMA GEMM + bias + LayerNorm + ReLU + residual ----------------
// Block 256 = 4 waves, 64 rows. LDS: Wt 128x(16+1) uint4 + A 64x(16+1) uint4 = 52224B
// -> 3 blocks/CU. Row stride 272B => 2-way bank aliasing only (free, m136).
// mfma_f32_16x16x32_bf16: A[m=lane&15][k=quad*8+j], B[n=lane&15][k=quad*8+j] (from Wt),
// C/D: col=lane&15, row=quad*4+reg.
template <bool RES, bool FINAL>
__global__ __launch_bounds__(256) void gemm_ln_kernel(
    const ushort* __restrict__ aggb, const ushort* __restrict__ Wt,
    const float* __restrict__ bias, const float* __restrict__ gamma,
    const float* __restrict__ beta, ushort* __restrict__ featb, float* __restrict__ out) {
    __shared__ uint4 sB[128 * 17];
    __shared__ uint4 sA[64 * 17];

    const uint4* Wg = (const uint4*)Wt;
    for (int i = threadIdx.x; i < 2048; i += 256) sB[(i >> 4) * 17 + (i & 15)] = Wg[i];

    int row0 = blockIdx.x * 64;
    int nrows = min(64, NN - row0);
    const uint4* Ag = (const uint4*)(aggb + (size_t)row0 * DD);
    for (int i = threadIdx.x; i < nrows * 16; i += 256) sA[(i >> 4) * 17 + (i & 15)] = Ag[i];
    for (int i = nrows * 16 + threadIdx.x; i < 64 * 16; i += 256)
        sA[(i >> 4) * 17 + (i & 15)] = make_uint4(0, 0, 0, 0);
    __syncthreads();

    int w = threadIdx.x >> 6, lane = threadIdx.x & 63;
    int q = lane >> 4, m = lane & 15;

    f32x4 acc[8];
#pragma unroll
    for (int t = 0; t < 8; ++t) acc[t] = (f32x4){0.f, 0.f, 0.f, 0.f};

#pragma unroll
    for (int kk = 0; kk < 4; ++kk) {
        bf16x8 af = *(const bf16x8*)&sA[(16 * w + m) * 17 + kk * 4 + q];
#pragma unroll
        for (int t = 0; t < 8; ++t) {
            bf16x8 bf = *(const bf16x8*)&sB[(16 * t + m) * 17 + kk * 4 + q];
            acc[t] = __builtin_amdgcn_mfma_f32_16x16x32_bf16(af, bf, acc[t], 0, 0, 0);
        }
    }

    // epilogue: bias, LN per output row (rows live across the 16 lanes of a quad)
    float s1[4] = {0.f, 0.f, 0.f, 0.f}, s2[4] = {0.f, 0.f, 0.f, 0.f};
#pragma unroll
    for (int t = 0; t < 8; ++t) {
        float b = bias[16 * t + m];
#pragma unroll
        for (int r = 0; r < 4; ++r) {
            float v = acc[t][r] + b;
            acc[t][r] = v;
            s1[r] += v;
            s2[r] += v * v;
        }
    }
#pragma unroll
    for (int off = 1; off <= 8; off <<= 1) {
#pragma unroll
        for (int r = 0; r < 4; ++r) {
            s1[r] += __shfl_xor(s1[r], off, 64);
            s2[r] += __shfl_xor(s2[r], off, 64);
        }
    }
    float mu[4], rstd[4];
#pragma unroll
    for (int r = 0; r < 4; ++r) {
        mu[r] = s1[r] * (1.f / 128.f);
        float var = s2[r] * (1.f / 128.f) - mu[r] * mu[r];
        rstd[r] = rsqrtf(var + LN_EPS);
    }
    int rowbase = row0 + 16 * w + q * 4;
#pragma unroll
    for (int t = 0; t < 8; ++t) {
        int col = 16 * t + m;
        float ga = gamma[col], be = beta[col];
#pragma unroll
        for (int r = 0; r < 4; ++r) {
            int row = rowbase + r;
            float o = fmaxf((acc[t][r] - mu[r]) * rstd[r] * ga + be, 0.f);
            if (row < NN) {
                size_t idx = (size_t)row * DD + col;
                if (RES) o += __uint_as_float(((uint)featb[idx]) << 16);
                if (FINAL) out[idx] = o;
                else featb[idx] = f2bf_bits(o);
            }
        }
    }
}

// ---------------- launch ----------------

extern "C" void kernel_launch(void* const* d_in, const int* in_sizes, int n_in,
                              void* d_out, int out_size, void* d_ws, size_t ws_size,
                              hipStream_t stream) {
    const float* x = (const float*)d_in[0];
    const int* edge = (const int*)d_in[1];
    const float* Ws = (const float*)d_in[2];
    const float* bs = (const float*)d_in[3];
    const float* gs = (const float*)d_in[4];
    const float* bes = (const float*)d_in[5];
    float* out = (float*)d_out;
    const int* src = edge;
    const int* dst = edge + NE;

    char* p = (char*)d_ws;
    int* counts = (int*)p;      p += (size_t)NN * 4;
    int* excl = (int*)p;        p += (size_t)NN * 4;
    int* bsums = (int*)p;       p += 256 * 4;
    int* row_ptr = (int*)p;     p += (size_t)(NN + 4) * 4;
    int* next_pos = (int*)p;    p += (size_t)NN * 4;
    float* dinv = (float*)p;    p += (size_t)NN * 4;
    int* src_sorted = (int*)p;  p += (size_t)NE * 4;
    float* nrm_sorted = (float*)p; p += (size_t)NE * 4;
    ushort* aggb = (ushort*)p;  p += (size_t)NN * DD * 2;   // bf16 agg output
    ushort* featb = (ushort*)p; p += (size_t)NN * DD * 2;   // bf16 feature/gather table
    ushort* Wt = (ushort*)p;    p += (size_t)3 * DD * DD * 2;  // bf16 W^T per layer

    zero_counts<<<196, 256, 0, stream>>>(counts);
    hist_kernel<<<NE / 256, 256, 0, stream>>>(dst, counts);
    scan_blocks<<<196, 256, 0, stream>>>(counts, excl, bsums);
    scan_sums_kernel<<<1, 256, 0, stream>>>(bsums, 196);
    finalize_kernel<<<196, 256, 0, stream>>>(excl, bsums, counts, row_ptr, next_pos, dinv);
    fill_kernel<<<NE / 256, 256, 0, stream>>>(src, dst, next_pos, dinv, src_sorted, nrm_sorted);

    wtcast_kernel<<<192, 256, 0, stream>>>(Ws, Wt);
    cast_kernel<<<NN * 64 / 256, 256, 0, stream>>>(x, featb);

    int gemm_grid = (NN + 63) / 64;  // 782
    for (int l = 0; l < 3; ++l) {
        agg_kernel<<<NN / 16, 256, 0, stream>>>(featb, row_ptr, src_sorted, nrm_sorted, dinv,
                                                aggb);
        const ushort* Wl = Wt + (size_t)l * DD * DD;
        const float* bl = bs + l * DD;
        const float* gl = gs + l * DD;
        const float* bel = bes + l * DD;
        if (l == 0)
            gemm_ln_kernel<false, false><<<gemm_grid, 256, 0, stream>>>(
                aggb, Wl, bl, gl, bel, featb, out);
        else if (l == 1)
            gemm_ln_kernel<true, false><<<gemm_grid, 256, 0, stream>>>(
                aggb, Wl, bl, gl, bel, featb, out);
        else
            gemm_ln_kernel<true, true><<<gemm_grid, 256, 0, stream>>>(
                aggb, Wl, bl, gl, bel, featb, out);
    }
}